// Round 14
// baseline (228.045 us; speedup 1.0000x reference)
//
#include <hip/hip_runtime.h>

typedef unsigned short u16;
typedef u16 u16x8 __attribute__((ext_vector_type(8)));
typedef _Float16 half2 __attribute__((ext_vector_type(2)));
typedef _Float16 h8v __attribute__((ext_vector_type(8)));
typedef float f4v __attribute__((ext_vector_type(4)));

union H8 { h8v v; half2 p[4]; };

// ---------- bf16 helpers ----------
static __device__ __forceinline__ float bf2f(u16 u) {
    union { unsigned int i; float f; } v;
    v.i = ((unsigned int)u) << 16;
    return v.f;
}
static __device__ __forceinline__ u16 f2bf(float f) {
    union { float f; unsigned int i; } v;
    v.f = f;
    unsigned int x = v.i;
    x += 0x7fffu + ((x >> 16) & 1u);   // RNE
    return (u16)(x >> 16);
}
static __device__ __forceinline__ float gld(int dt, const void* p, int i) {
    return dt ? ((const float*)p)[i] : bf2f(((const u16*)p)[i]);
}
static __device__ __forceinline__ int detect_dt(const void* coords) {
    u16 v = ((const u16*)coords)[threadIdx.x & 63];
    int e = (v >> 7) & 0xFF;
    bool inr = (e >= 90) && (e <= 126);
    unsigned long long m = __ballot(inr);
    return (__popcll(m) >= 56) ? 0 : 1;   // 0=bf16, 1=f32
}
static __device__ __forceinline__ half2 pk(float a, float b) {
    return __builtin_bit_cast(half2, __builtin_amdgcn_cvt_pkrtz(a, b));
}

// compiler-reordering barrier only (no instructions emitted). Correctness
// basis in single-wave workgroups: DS ops from one wave execute in order,
// and per-lane write/read addresses alias so the compiler keeps program
// order; global loads (different addr space) remain free to hoist.
#define CBAR() asm volatile("" ::: "memory")

// ---------- ws layout (bytes) ----------
#define WF_OFF        64u
#define PLANES_S_OFF  34304u         // 3*524288 u16
#define VOL_S_OFF     3180032u       // 2097152 u16
#define LINES_S_OFF   7374336u       // 12288 u16
#define PART_OFF      7398912u       // 256*4096 u16 = 2 MB
#define TOT_OFF       9496064u       // 4096 u32
#define ORDER_OFF     9512448u       // 4*M

#define NBUCK 4096
#define HBLOCKS 256

// weight region (float units from wbase):
//   Wt  f16[3][32 o][32 c]   | bv f32[96] | W1t f16[128][64 pad]
//   b1v f32[128] | W2v f32[128] | b2v f32[1]

// =====================================================================
// spatial key
// =====================================================================
static __device__ __forceinline__ int make_key3(float x, float y, float z) {
    int kx = min(max((int)((x + 1.0f) * 8.0f), 0), 15);
    int ky = min(max((int)((y + 1.0f) * 8.0f), 0), 15);
    int kz = min(max((int)((z + 1.0f) * 8.0f), 0), 15);
    return (kz * 16 + ky) * 16 + kx;
}
static __device__ __forceinline__ int make_key(int dt, const void* coords, int p) {
    return make_key3(gld(dt, coords, p * 3 + 0), gld(dt, coords, p * 3 + 1),
                     gld(dt, coords, p * 3 + 2));
}

// =====================================================================
// weight packing (f16 MFMA layouts)
// =====================================================================
static __device__ __forceinline__ void weights_work(
    int dt, int r,
    const void* Wx, const void* bx, const void* Wy, const void* by,
    const void* Wz, const void* bz, const void* W1, const void* b1,
    const void* W2, const void* b2, float* wbase)
{
    _Float16* WtH = (_Float16*)wbase;
    float*    bv  = wbase + 1536;
    _Float16* W1H = (_Float16*)(wbase + 1632);
    float*    b1v = wbase + 5728;
    float*    W2v = wbase + 5856;
    float*    b2v = wbase + 5984;
    if (r < 3072) {
        int m = r >> 10, idx = r & 1023;
        int o = idx >> 5, c = idx & 31;
        const void* s = (m == 0) ? Wx : (m == 1) ? Wy : Wz;
        WtH[r] = (_Float16)gld(dt, s, c * 32 + o);   // Wt[m][o][c] = W[c][o]
    } else if (r < 3168) {
        int q2 = r - 3072;
        int m = q2 >> 5, c = q2 & 31;
        const void* s = (m == 0) ? bx : (m == 1) ? by : bz;
        bv[q2] = gld(dt, s, c);
    } else if (r < 11360) {
        int idx = r - 3168;                 // j*64 + i
        int j = idx >> 6, i = idx & 63;
        W1H[idx] = (i < 40) ? (_Float16)gld(dt, W1, i * 128 + j) : (_Float16)0.0f;
    } else if (r < 11488) {
        b1v[r - 11360] = gld(dt, b1, r - 11360);
    } else if (r < 11616) {
        W2v[r - 11488] = gld(dt, W2, r - 11488);
    } else if (r == 11616) {
        b2v[0] = gld(dt, b2, 0);
    }
}

// =====================================================================
// fused prep: grid transpose (0..1797) + weights (1798..1843)
//           + histogram partials u16, plain stores (1844..2099)
// =====================================================================
__global__ __launch_bounds__(256) void kp_prep_all(
    const void* __restrict__ coords,
    const void* __restrict__ lx, const void* __restrict__ ly,
    const void* __restrict__ lz,
    const void* __restrict__ pxy, const void* __restrict__ pyz,
    const void* __restrict__ pxz, const void* __restrict__ vol,
    const void* __restrict__ Wx, const void* __restrict__ bx,
    const void* __restrict__ Wy, const void* __restrict__ by,
    const void* __restrict__ Wz, const void* __restrict__ bz,
    const void* __restrict__ W1, const void* __restrict__ b1,
    const void* __restrict__ W2, const void* __restrict__ b2,
    float* __restrict__ wbase,
    u16* __restrict__ planes_s, u16* __restrict__ vol_s,
    u16* __restrict__ lines_s, u16* __restrict__ part, int M)
{
    __shared__ unsigned int lh[NBUCK];
    int dt = detect_dt(coords);
    int blk = blockIdx.x;
    if (blk < 1798) {
        int t = blk * 256 + threadIdx.x;   // [0, 460288)
        u16x8 v;
        if (t < 196608) {                 // planes: 8 consecutive out u16
            int o = t * 8;
            int pl = o >> 19;
            int r  = o & 524287;
            int pos = r >> 5, c0 = r & 31;
            const void* src = (pl == 0) ? pxy : (pl == 1) ? pyz : pxz;
#pragma unroll
            for (int i = 0; i < 8; ++i)
                v[i] = dt ? f2bf(((const float*)src)[(c0 + i) * 16384 + pos])
                          : ((const u16*)src)[(c0 + i) * 16384 + pos];
            *(u16x8*)(planes_s + o) = v;
        } else if (t < 458752) {          // volume: thread = one pos, 8 channels
            int pos = t - 196608;
#pragma unroll
            for (int c = 0; c < 8; ++c)
                v[c] = dt ? f2bf(((const float*)vol)[c * 262144 + pos])
                          : ((const u16*)vol)[c * 262144 + pos];
            *(u16x8*)(vol_s + pos * 8) = v;
        } else {                          // lines
            int o = (t - 458752) * 8;
            int l = o >> 12, rr = o & 4095;
            int pos = rr >> 5, c0 = rr & 31;
            const void* src = (l == 0) ? lx : (l == 1) ? ly : lz;
#pragma unroll
            for (int i = 0; i < 8; ++i)
                v[i] = dt ? f2bf(((const float*)src)[(c0 + i) * 128 + pos])
                          : ((const u16*)src)[(c0 + i) * 128 + pos];
            *(u16x8*)(lines_s + o) = v;
        }
    } else if (blk < 1844) {
        int r = (blk - 1798) * 256 + threadIdx.x;   // [0, 11776)
        weights_work(dt, r, Wx, bx, Wy, by, Wz, bz, W1, b1, W2, b2, wbase);
    } else {
        int b = blk - 1844;               // [0, 256)
        for (int i = threadIdx.x; i < NBUCK; i += 256) lh[i] = 0u;
        __syncthreads();
        for (int p = b * 256 + threadIdx.x; p < M; p += HBLOCKS * 256)
            atomicAdd(&lh[make_key(dt, coords, p)], 1u);
        __syncthreads();
        for (int i = threadIdx.x; i < NBUCK; i += 256)
            part[b * NBUCK + i] = (u16)lh[i];
    }
}

// =====================================================================
// column scan: part[b][bkt] (u16) -> exclusive prefix over b (in place),
// tot[bkt] = column total. Loads coalesced per iteration (64 lanes on
// consecutive buckets).
// =====================================================================
__global__ __launch_bounds__(64) void kp_colscan(
    u16* __restrict__ part, unsigned int* __restrict__ tot)
{
    int bkt = blockIdx.x * 64 + threadIdx.x;   // 64 blocks x 64
    unsigned int run = 0;
#pragma unroll 8
    for (int k = 0; k < HBLOCKS; ++k) {
        unsigned int v = part[k * NBUCK + bkt];
        part[k * NBUCK + bkt] = (u16)run;
        run += v;
    }
    tot[bkt] = run;
}

// =====================================================================
// deterministic scatter: 256 blocks, LDS counters, no global atomics.
// =====================================================================
__global__ __launch_bounds__(256) void kp_scatter_det(
    const void* __restrict__ coords, const u16* __restrict__ part,
    const unsigned int* __restrict__ tot,
    int* __restrict__ order, int M)
{
    __shared__ unsigned int cnt[NBUCK];
    __shared__ unsigned int psum[256];
    int b = blockIdx.x;          // [0, 256)
    int t = threadIdx.x;
    unsigned int bs[16];
    unsigned int s = 0;
#pragma unroll
    for (int i = 0; i < 16; ++i) {
        bs[i] = tot[t * 16 + i];
        s += bs[i];
    }
    psum[t] = s;
    __syncthreads();
    if (t == 0) {
        unsigned int run = 0;
        for (int i = 0; i < 256; ++i) { unsigned int v = psum[i]; psum[i] = run; run += v; }
    }
    __syncthreads();
    unsigned int run = psum[t];
#pragma unroll
    for (int i = 0; i < 16; ++i) {
        int bkt = t * 16 + i;
        cnt[bkt] = run + (unsigned int)part[b * NBUCK + bkt];
        run += bs[i];
    }
    __syncthreads();
    int dt = detect_dt(coords);
    for (int p = b * 256 + t; p < M; p += HBLOCKS * 256) {
        int key = make_key(dt, coords, p);
        unsigned int pos = atomicAdd(&cnt[key], 1u);
        order[pos] = p;
    }
}

// =====================================================================
// shared math
// =====================================================================
struct Samp { int i0, i1; float w0, w1; };

static __device__ __forceinline__ Samp make_samp(float g, int N) {
    float ix = (g + 1.0f) * 0.5f * (float)(N - 1);
    float fl = floorf(ix);
    float w  = ix - fl;
    int i  = (int)fl;
    int i1 = i + 1;
    float v0 = (i  >= 0 && i  < N) ? 1.0f : 0.0f;
    float v1 = (i1 >= 0 && i1 < N) ? 1.0f : 0.0f;
    Samp s;
    s.w0 = (1.0f - w) * v0;
    s.w1 = w * v1;
    s.i0 = min(max(i, 0), N - 1);
    s.i1 = min(max(i1, 0), N - 1);
    return s;
}

#define MFMA16(a, b, c) __builtin_amdgcn_mfma_f32_16x16x32_f16((a), (b), (c), 0, 0, 0)

#define SRE 40
#define SR2 72

// one product term: interp -> LDS E (f16, relu'd) -> MFMA ta,tb -> feat += ta*tb
// NO barriers: single-wave in-order DS + per-lane aliasing keeps LDS order;
// global loads of later terms remain free to hoist above this term's MFMAs.
static __device__ __forceinline__ void term_mfma(
    int lane, const u16* __restrict__ Ls, const Samp& sl,
    const u16* __restrict__ Ps, const Samp& sa, const Samp& sb,
    const _Float16* __restrict__ Wt, const float* __restrict__ bvt,
    _Float16* El, _Float16* Ep, float (&feat)[4][2][4])
{
    int q = lane >> 4, l15 = lane & 15;
    const u16x8* l0  = (const u16x8*)(Ls + sl.i0 * 32);
    const u16x8* l1  = (const u16x8*)(Ls + sl.i1 * 32);
    const u16x8* p00 = (const u16x8*)(Ps + (sb.i0 * 128 + sa.i0) * 32);
    const u16x8* p01 = (const u16x8*)(Ps + (sb.i0 * 128 + sa.i1) * 32);
    const u16x8* p10 = (const u16x8*)(Ps + (sb.i1 * 128 + sa.i0) * 32);
    const u16x8* p11 = (const u16x8*)(Ps + (sb.i1 * 128 + sa.i1) * 32);
    float w00 = sb.w0 * sa.w0, w01 = sb.w0 * sa.w1;
    float w10 = sb.w1 * sa.w0, w11 = sb.w1 * sa.w1;
#pragma unroll
    for (int cc = 0; cc < 4; ++cc) {
        u16x8 A0 = l0[cc], A1 = l1[cc];
        u16x8 Q00 = p00[cc], Q01 = p01[cc], Q10 = p10[cc], Q11 = p11[cc];
        H8 hl, hp;
#pragma unroll
        for (int kk = 0; kk < 4; ++kk) {
            int k0 = 2 * kk, k1 = k0 + 1;
            float el0 = sl.w0 * bf2f(A0[k0]) + sl.w1 * bf2f(A1[k0]);
            float el1 = sl.w0 * bf2f(A0[k1]) + sl.w1 * bf2f(A1[k1]);
            float ep0 = w00 * bf2f(Q00[k0]) + w01 * bf2f(Q01[k0])
                      + w10 * bf2f(Q10[k0]) + w11 * bf2f(Q11[k0]);
            float ep1 = w00 * bf2f(Q00[k1]) + w01 * bf2f(Q01[k1])
                      + w10 * bf2f(Q10[k1]) + w11 * bf2f(Q11[k1]);
            hl.p[kk] = pk(fmaxf(el0, 0.0f), fmaxf(el1, 0.0f));
            hp.p[kk] = pk(fmaxf(ep0, 0.0f), fmaxf(ep1, 0.0f));
        }
        *(h8v*)&El[lane * SRE + cc * 8] = hl.v;
        *(h8v*)&Ep[lane * SRE + cc * 8] = hp.v;
    }
    h8v bf0 = *(const h8v*)&Wt[(l15) * 32 + q * 8];
    h8v bf1 = *(const h8v*)&Wt[(16 + l15) * 32 + q * 8];
    float bb0 = bvt[l15], bb1 = bvt[16 + l15];
    f4v c0 = {bb0, bb0, bb0, bb0};
    f4v c1 = {bb1, bb1, bb1, bb1};
#pragma unroll
    for (int mt = 0; mt < 4; ++mt) {
        h8v aL = *(const h8v*)&El[(mt * 16 + l15) * SRE + q * 8];
        h8v aP = *(const h8v*)&Ep[(mt * 16 + l15) * SRE + q * 8];
        f4v ta0 = MFMA16(aL, bf0, c0);
        f4v tb0 = MFMA16(aP, bf0, c0);
        f4v ta1 = MFMA16(aL, bf1, c1);
        f4v tb1 = MFMA16(aP, bf1, c1);
#pragma unroll
        for (int r = 0; r < 4; ++r) {
            feat[mt][0][r] += ta0[r] * tb0[r];
            feat[mt][1][r] += ta1[r] * tb1[r];
        }
    }
}

// =====================================================================
// MFMA main — single-wave blocks, barrier-free LDS, LDS 10240 B
// =====================================================================
__global__ __launch_bounds__(64, 4) void kp_main_mfma(
    const void* __restrict__ coords, const int* __restrict__ order,
    const u16* __restrict__ planes_s, const u16* __restrict__ vol_s,
    const u16* __restrict__ lines_s,
    const float* __restrict__ wbase,
    void* __restrict__ out, int M)
{
    __shared__ _Float16 eb[5120];   // El[2560] | Ep[2560]; reused as E2[64*72=4608]
    int dt = detect_dt(coords);
    const _Float16* WtH = (const _Float16*)wbase;
    const float*    bv  = wbase + 1536;
    const _Float16* W1H = (const _Float16*)(wbase + 1632);
    const float*    b1v = wbase + 5728;
    const float*    W2v = wbase + 5856;
    const float*    b2v = wbase + 5984;

    int lane = threadIdx.x;
    int q = lane >> 4, l15 = lane & 15;
    _Float16* El = eb;
    _Float16* Ep = eb + 2560;
    _Float16* E2 = eb;
    float* res = (float*)(eb + 4608);   // 64 floats in E2's unused tail

    int p = blockIdx.x * 64 + lane;
    p = min(p, M - 1);
    int sp = order[p];

    float x = gld(dt, coords, sp * 3 + 0);
    float y = gld(dt, coords, sp * 3 + 1);
    float z = gld(dt, coords, sp * 3 + 2);

    Samp sx = make_samp(x, 128), sy = make_samp(y, 128), sz = make_samp(z, 128);

    float feat[4][2][4];
#pragma unroll
    for (int mt = 0; mt < 4; ++mt)
#pragma unroll
        for (int n = 0; n < 2; ++n)
#pragma unroll
            for (int r = 0; r < 4; ++r) feat[mt][n][r] = 0.0f;

    term_mfma(lane, lines_s + 0 * 4096, sx, planes_s + 1 * 524288, sy, sz,
              WtH + 0,    bv + 0,  El, Ep, feat);
    term_mfma(lane, lines_s + 1 * 4096, sy, planes_s + 2 * 524288, sx, sz,
              WtH + 1024, bv + 32, El, Ep, feat);
    term_mfma(lane, lines_s + 2 * 4096, sz, planes_s + 0 * 524288, sx, sy,
              WtH + 2048, bv + 64, El, Ep, feat);

    CBAR();   // El/Ep -> E2 buffer reuse: forbid compiler proving disjointness

#pragma unroll
    for (int mt = 0; mt < 4; ++mt)
#pragma unroll
        for (int n = 0; n < 2; ++n)
#pragma unroll
            for (int r = 0; r < 4; ++r)
                E2[(mt * 16 + q * 4 + r) * SR2 + n * 16 + l15] =
                    (_Float16)feat[mt][n][r];
    {
        Samp vx = make_samp(x, 64), vy = make_samp(y, 64), vz = make_samp(z, 64);
        float vf[8];
#pragma unroll
        for (int c = 0; c < 8; ++c) vf[c] = 0.0f;
#pragma unroll
        for (int corner = 0; corner < 8; ++corner) {
            int dx = corner & 1, dy = (corner >> 1) & 1, dz = corner >> 2;
            int xi = dx ? vx.i1 : vx.i0;
            int yi = dy ? vy.i1 : vy.i0;
            int zi = dz ? vz.i1 : vz.i0;
            float w = (dx ? vx.w1 : vx.w0) * (dy ? vy.w1 : vy.w0) * (dz ? vz.w1 : vz.w0);
            u16x8 v = *(const u16x8*)(vol_s + (((zi * 64) + yi) * 64 + xi) * 8);
#pragma unroll
            for (int c = 0; c < 8; ++c)
                vf[c] = fmaf(w, bf2f(v[c]), vf[c]);
        }
        H8 hv;
#pragma unroll
        for (int k = 0; k < 4; ++k) hv.p[k] = pk(vf[2 * k], vf[2 * k + 1]);
        *(h8v*)&E2[lane * SR2 + 32] = hv.v;
        h8v zz = {};
        *(h8v*)&E2[lane * SR2 + 40] = zz;
        *(h8v*)&E2[lane * SR2 + 48] = zz;
        *(h8v*)&E2[lane * SR2 + 56] = zz;
    }
    CBAR();

    h8v af[4][2];
#pragma unroll
    for (int mt = 0; mt < 4; ++mt)
#pragma unroll
        for (int ks = 0; ks < 2; ++ks)
            af[mt][ks] = *(const h8v*)&E2[(mt * 16 + l15) * SR2 + ks * 32 + q * 8];

    float s[4][4];
#pragma unroll
    for (int mt = 0; mt < 4; ++mt)
#pragma unroll
        for (int r = 0; r < 4; ++r) s[mt][r] = 0.0f;

#pragma unroll
    for (int NT = 0; NT < 8; ++NT) {
        int o = NT * 16 + l15;
        h8v b0 = *(const h8v*)&W1H[o * 64 + q * 8];
        h8v b1f = *(const h8v*)&W1H[o * 64 + 32 + q * 8];
        float w2 = W2v[o];
        float bb = b1v[o];
        f4v cinit = {bb, bb, bb, bb};
#pragma unroll
        for (int mt = 0; mt < 4; ++mt) {
            f4v c = MFMA16(af[mt][0], b0, cinit);
            c = MFMA16(af[mt][1], b1f, c);
#pragma unroll
            for (int r = 0; r < 4; ++r)
                s[mt][r] = fmaf(fmaxf(c[r], 0.0f), w2, s[mt][r]);
        }
    }
#pragma unroll
    for (int mt = 0; mt < 4; ++mt)
#pragma unroll
        for (int r = 0; r < 4; ++r) {
            float v = s[mt][r];
            v += __shfl_xor(v, 1);
            v += __shfl_xor(v, 2);
            v += __shfl_xor(v, 4);
            v += __shfl_xor(v, 8);
            s[mt][r] = v;
        }
    CBAR();   // res overlaps E2 tail (disjoint, but keep order pinned)
    if (l15 == 0) {
#pragma unroll
        for (int mt = 0; mt < 4; ++mt)
#pragma unroll
            for (int r = 0; r < 4; ++r)
                res[mt * 16 + q * 4 + r] = s[mt][r];
    }
    CBAR();
    float rr = res[lane] + b2v[0];
    if (dt) ((float*)out)[sp] = rr;
    else    ((u16*)out)[sp] = f2bf(rr);
}

// =====================================================================
// fallback path (ws too small): weights-only prep + direct gathers
// =====================================================================
__global__ void kp_prep_weights_fb(
    const void* __restrict__ coords,
    const void* __restrict__ Wx, const void* __restrict__ bx,
    const void* __restrict__ Wy, const void* __restrict__ by,
    const void* __restrict__ Wz, const void* __restrict__ bz,
    const void* __restrict__ W1, const void* __restrict__ b1,
    const void* __restrict__ W2, const void* __restrict__ b2,
    float* __restrict__ wbase)
{
    int dt = detect_dt(coords);
    int t = blockIdx.x * blockDim.x + threadIdx.x;
    weights_work(dt, t, Wx, bx, Wy, by, Wz, bz, W1, b1, W2, b2, wbase);
}

__global__ __launch_bounds__(256) void kp_main_direct(
    const void* __restrict__ coords,
    const void* __restrict__ lx, const void* __restrict__ ly, const void* __restrict__ lz,
    const void* __restrict__ pxy, const void* __restrict__ pyz, const void* __restrict__ pxz,
    const void* __restrict__ vol,
    const float* __restrict__ wbase,
    void* __restrict__ out, int M)
{
    int dt = detect_dt(coords);
    const _Float16* WtH = (const _Float16*)wbase;
    const float*    bv  = wbase + 1536;
    const _Float16* W1H = (const _Float16*)(wbase + 1632);
    const float*    b1v = wbase + 5728;
    const float*    W2v = wbase + 5856;
    const float*    b2v = wbase + 5984;

    int p = blockIdx.x * 256 + threadIdx.x;
    p = min(p, M - 1);

    float x = gld(dt, coords, p * 3 + 0);
    float y = gld(dt, coords, p * 3 + 1);
    float z = gld(dt, coords, p * 3 + 2);

    Samp sx = make_samp(x, 128), sy = make_samp(y, 128), sz = make_samp(z, 128);

    float feat[40];
#pragma unroll
    for (int o = 0; o < 40; ++o) feat[o] = 0.0f;

    const void* Ls[3] = {lx, ly, lz};
    const void* Psv[3] = {pyz, pxz, pxy};
    Samp sl3[3] = {sx, sy, sz};
    Samp sa3[3] = {sy, sx, sx};
    Samp sb3[3] = {sz, sz, sy};
#pragma unroll 1
    for (int m = 0; m < 3; ++m) {
        float ta[32], tb[32];
        const float* bvt = bv + m * 32;
        const _Float16* Wt = WtH + m * 1024;
#pragma unroll
        for (int o = 0; o < 32; ++o) { ta[o] = bvt[o]; tb[o] = bvt[o]; }
        Samp sl = sl3[m], sa = sa3[m], sb = sb3[m];
        float w00 = sb.w0 * sa.w0, w01 = sb.w0 * sa.w1;
        float w10 = sb.w1 * sa.w0, w11 = sb.w1 * sa.w1;
        int i00 = sb.i0 * 128 + sa.i0, i01 = sb.i0 * 128 + sa.i1;
        int i10 = sb.i1 * 128 + sa.i0, i11 = sb.i1 * 128 + sa.i1;
#pragma unroll 1
        for (int c = 0; c < 32; ++c) {
            float el = sl.w0 * gld(dt, Ls[m], c * 128 + sl.i0)
                     + sl.w1 * gld(dt, Ls[m], c * 128 + sl.i1);
            float ep = w00 * gld(dt, Psv[m], c * 16384 + i00)
                     + w01 * gld(dt, Psv[m], c * 16384 + i01)
                     + w10 * gld(dt, Psv[m], c * 16384 + i10)
                     + w11 * gld(dt, Psv[m], c * 16384 + i11);
            float r1 = fmaxf(el, 0.0f), r2 = fmaxf(ep, 0.0f);
#pragma unroll
            for (int o = 0; o < 32; ++o) {
                float w = (float)Wt[o * 32 + c];
                ta[o] = fmaf(r1, w, ta[o]);
                tb[o] = fmaf(r2, w, tb[o]);
            }
        }
#pragma unroll
        for (int o = 0; o < 32; ++o) feat[o] = fmaf(ta[o], tb[o], feat[o]);
    }

    Samp vx = make_samp(x, 64), vy = make_samp(y, 64), vz = make_samp(z, 64);
#pragma unroll 1
    for (int corner = 0; corner < 8; ++corner) {
        int dx = corner & 1, dy = (corner >> 1) & 1, dz = corner >> 2;
        int xi = dx ? vx.i1 : vx.i0;
        int yi = dy ? vy.i1 : vy.i0;
        int zi = dz ? vz.i1 : vz.i0;
        float w = (dx ? vx.w1 : vx.w0) * (dy ? vy.w1 : vy.w0) * (dz ? vz.w1 : vz.w0);
        int pos = ((zi * 64) + yi) * 64 + xi;
#pragma unroll
        for (int c = 0; c < 8; ++c)
            feat[32 + c] = fmaf(w, gld(dt, vol, c * 262144 + pos), feat[32 + c]);
    }

    float acc_out = b2v[0];
#pragma unroll 2
    for (int j = 0; j < 128; ++j) {
        float acc = b1v[j];
        const _Float16* wr = W1H + j * 64;
#pragma unroll
        for (int i = 0; i < 40; ++i)
            acc = fmaf(feat[i], (float)wr[i], acc);
        acc_out = fmaf(fmaxf(acc, 0.0f), W2v[j], acc_out);
    }
    if (dt) ((float*)out)[p] = acc_out;
    else    ((u16*)out)[p] = f2bf(acc_out);
}

// =====================================================================
extern "C" void kernel_launch(void* const* d_in, const int* in_sizes, int n_in,
                              void* d_out, int out_size, void* d_ws, size_t ws_size,
                              hipStream_t stream) {
    const void* coords = d_in[0];
    const void* lx  = d_in[1];
    const void* ly  = d_in[2];
    const void* lz  = d_in[3];
    const void* pxy = d_in[4];
    const void* pyz = d_in[5];
    const void* pxz = d_in[6];
    const void* vol = d_in[7];
    const void* Wx  = d_in[8];
    const void* bx  = d_in[9];
    const void* Wy  = d_in[10];
    const void* by  = d_in[11];
    const void* Wz  = d_in[12];
    const void* bz  = d_in[13];
    const void* W1  = d_in[14];
    const void* b1  = d_in[15];
    const void* W2  = d_in[16];
    const void* b2  = d_in[17];

    int M = in_sizes[0] / 3;

    char* ws = (char*)d_ws;
    float*        wbase    = (float*)(ws + WF_OFF);
    u16*          planes_s = (u16*)(ws + PLANES_S_OFF);
    u16*          vol_s    = (u16*)(ws + VOL_S_OFF);
    u16*          lines_s  = (u16*)(ws + LINES_S_OFF);
    u16*          part     = (u16*)(ws + PART_OFF);
    unsigned int* tot      = (unsigned int*)(ws + TOT_OFF);
    int*          order    = (int*)(ws + ORDER_OFF);

    size_t need_sorted = (size_t)ORDER_OFF + (size_t)M * 4u;

    if (ws_size >= need_sorted) {
        kp_prep_all<<<2100, 256, 0, stream>>>(coords, lx, ly, lz, pxy, pyz, pxz, vol,
                                              Wx, bx, Wy, by, Wz, bz, W1, b1, W2, b2,
                                              wbase, planes_s, vol_s, lines_s, part, M);
        kp_colscan<<<64, 64, 0, stream>>>(part, tot);
        kp_scatter_det<<<HBLOCKS, 256, 0, stream>>>(coords, part, tot, order, M);
        int blocks64 = (M + 63) / 64;
        kp_main_mfma<<<blocks64, 64, 0, stream>>>(coords, order,
                                                  planes_s, vol_s,
                                                  lines_s, wbase, d_out, M);
    } else {
        int blocks = (M + 255) / 256;
        kp_prep_weights_fb<<<46, 256, 0, stream>>>(coords, Wx, bx, Wy, by, Wz, bz,
                                                   W1, b1, W2, b2, wbase);
        kp_main_direct<<<blocks, 256, 0, stream>>>(coords, lx, ly, lz, pxy, pyz, pxz,
                                                   vol, wbase, d_out, M);
    }
}

// Round 15
// 201.910 us; speedup vs baseline: 1.1294x; 1.1294x over previous
//
#include <hip/hip_runtime.h>

typedef unsigned short u16;
typedef u16 u16x8 __attribute__((ext_vector_type(8)));
typedef _Float16 half2 __attribute__((ext_vector_type(2)));
typedef _Float16 h8v __attribute__((ext_vector_type(8)));
typedef float f4v __attribute__((ext_vector_type(4)));

union H8 { h8v v; half2 p[4]; };

// ---------- bf16 helpers ----------
static __device__ __forceinline__ float bf2f(u16 u) {
    union { unsigned int i; float f; } v;
    v.i = ((unsigned int)u) << 16;
    return v.f;
}
static __device__ __forceinline__ u16 f2bf(float f) {
    union { float f; unsigned int i; } v;
    v.f = f;
    unsigned int x = v.i;
    x += 0x7fffu + ((x >> 16) & 1u);   // RNE
    return (u16)(x >> 16);
}
static __device__ __forceinline__ float gld(int dt, const void* p, int i) {
    return dt ? ((const float*)p)[i] : bf2f(((const u16*)p)[i]);
}
static __device__ __forceinline__ int detect_dt(const void* coords) {
    u16 v = ((const u16*)coords)[threadIdx.x & 63];
    int e = (v >> 7) & 0xFF;
    bool inr = (e >= 90) && (e <= 126);
    unsigned long long m = __ballot(inr);
    return (__popcll(m) >= 56) ? 0 : 1;   // 0=bf16, 1=f32
}
static __device__ __forceinline__ half2 pk(float a, float b) {
    return __builtin_bit_cast(half2, __builtin_amdgcn_cvt_pkrtz(a, b));
}

// compiler-reordering barrier only (no instructions emitted). Correctness
// basis in single-wave workgroups: DS ops from one wave execute in order,
// and per-lane write/read addresses alias so the compiler keeps program
// order; global loads (different addr space) remain free to hoist.
#define CBAR() asm volatile("" ::: "memory")

// ---------- ws layout (bytes) ----------
#define WF_OFF        64u
#define PLANES_S_OFF  34304u         // 3*524288 u16
#define VOL_S_OFF     3180032u       // 2097152 u16
#define LINES_S_OFF   7374336u       // 12288 u16
#define PART_OFF      7398912u       // 256*4096 u16 = 2 MB
#define TOT_OFF       9496064u       // 4096 u32
#define ORDER_OFF     9512448u       // 4*M

#define NBUCK 4096
#define HBLOCKS 256

// weight region (float units from wbase):
//   Wt  f16[3][32 o][32 c]   | bv f32[96] | W1t f16[128][64 pad]
//   b1v f32[128] | W2v f32[128] | b2v f32[1]

// =====================================================================
// spatial key
// =====================================================================
static __device__ __forceinline__ int make_key3(float x, float y, float z) {
    int kx = min(max((int)((x + 1.0f) * 8.0f), 0), 15);
    int ky = min(max((int)((y + 1.0f) * 8.0f), 0), 15);
    int kz = min(max((int)((z + 1.0f) * 8.0f), 0), 15);
    return (kz * 16 + ky) * 16 + kx;
}
static __device__ __forceinline__ int make_key(int dt, const void* coords, int p) {
    return make_key3(gld(dt, coords, p * 3 + 0), gld(dt, coords, p * 3 + 1),
                     gld(dt, coords, p * 3 + 2));
}

// =====================================================================
// weight packing (f16 MFMA layouts)
// =====================================================================
static __device__ __forceinline__ void weights_work(
    int dt, int r,
    const void* Wx, const void* bx, const void* Wy, const void* by,
    const void* Wz, const void* bz, const void* W1, const void* b1,
    const void* W2, const void* b2, float* wbase)
{
    _Float16* WtH = (_Float16*)wbase;
    float*    bv  = wbase + 1536;
    _Float16* W1H = (_Float16*)(wbase + 1632);
    float*    b1v = wbase + 5728;
    float*    W2v = wbase + 5856;
    float*    b2v = wbase + 5984;
    if (r < 3072) {
        int m = r >> 10, idx = r & 1023;
        int o = idx >> 5, c = idx & 31;
        const void* s = (m == 0) ? Wx : (m == 1) ? Wy : Wz;
        WtH[r] = (_Float16)gld(dt, s, c * 32 + o);   // Wt[m][o][c] = W[c][o]
    } else if (r < 3168) {
        int q2 = r - 3072;
        int m = q2 >> 5, c = q2 & 31;
        const void* s = (m == 0) ? bx : (m == 1) ? by : bz;
        bv[q2] = gld(dt, s, c);
    } else if (r < 11360) {
        int idx = r - 3168;                 // j*64 + i
        int j = idx >> 6, i = idx & 63;
        W1H[idx] = (i < 40) ? (_Float16)gld(dt, W1, i * 128 + j) : (_Float16)0.0f;
    } else if (r < 11488) {
        b1v[r - 11360] = gld(dt, b1, r - 11360);
    } else if (r < 11616) {
        W2v[r - 11488] = gld(dt, W2, r - 11488);
    } else if (r == 11616) {
        b2v[0] = gld(dt, b2, 0);
    }
}

// =====================================================================
// fused prep: grid transpose (0..1797) + weights (1798..1843)
//           + histogram partials u16, plain stores (1844..2099)
// =====================================================================
__global__ __launch_bounds__(256) void kp_prep_all(
    const void* __restrict__ coords,
    const void* __restrict__ lx, const void* __restrict__ ly,
    const void* __restrict__ lz,
    const void* __restrict__ pxy, const void* __restrict__ pyz,
    const void* __restrict__ pxz, const void* __restrict__ vol,
    const void* __restrict__ Wx, const void* __restrict__ bx,
    const void* __restrict__ Wy, const void* __restrict__ by,
    const void* __restrict__ Wz, const void* __restrict__ bz,
    const void* __restrict__ W1, const void* __restrict__ b1,
    const void* __restrict__ W2, const void* __restrict__ b2,
    float* __restrict__ wbase,
    u16* __restrict__ planes_s, u16* __restrict__ vol_s,
    u16* __restrict__ lines_s, u16* __restrict__ part, int M)
{
    __shared__ unsigned int lh[NBUCK];
    int dt = detect_dt(coords);
    int blk = blockIdx.x;
    if (blk < 1798) {
        int t = blk * 256 + threadIdx.x;   // [0, 460288)
        u16x8 v;
        if (t < 196608) {                 // planes: 8 consecutive out u16
            int o = t * 8;
            int pl = o >> 19;
            int r  = o & 524287;
            int pos = r >> 5, c0 = r & 31;
            const void* src = (pl == 0) ? pxy : (pl == 1) ? pyz : pxz;
#pragma unroll
            for (int i = 0; i < 8; ++i)
                v[i] = dt ? f2bf(((const float*)src)[(c0 + i) * 16384 + pos])
                          : ((const u16*)src)[(c0 + i) * 16384 + pos];
            *(u16x8*)(planes_s + o) = v;
        } else if (t < 458752) {          // volume: thread = one pos, 8 channels
            int pos = t - 196608;
#pragma unroll
            for (int c = 0; c < 8; ++c)
                v[c] = dt ? f2bf(((const float*)vol)[c * 262144 + pos])
                          : ((const u16*)vol)[c * 262144 + pos];
            *(u16x8*)(vol_s + pos * 8) = v;
        } else {                          // lines
            int o = (t - 458752) * 8;
            int l = o >> 12, rr = o & 4095;
            int pos = rr >> 5, c0 = rr & 31;
            const void* src = (l == 0) ? lx : (l == 1) ? ly : lz;
#pragma unroll
            for (int i = 0; i < 8; ++i)
                v[i] = dt ? f2bf(((const float*)src)[(c0 + i) * 128 + pos])
                          : ((const u16*)src)[(c0 + i) * 128 + pos];
            *(u16x8*)(lines_s + o) = v;
        }
    } else if (blk < 1844) {
        int r = (blk - 1798) * 256 + threadIdx.x;   // [0, 11776)
        weights_work(dt, r, Wx, bx, Wy, by, Wz, bz, W1, b1, W2, b2, wbase);
    } else {
        int b = blk - 1844;               // [0, 256)
        for (int i = threadIdx.x; i < NBUCK; i += 256) lh[i] = 0u;
        __syncthreads();
        for (int p = b * 256 + threadIdx.x; p < M; p += HBLOCKS * 256)
            atomicAdd(&lh[make_key(dt, coords, p)], 1u);
        __syncthreads();
        for (int i = threadIdx.x; i < NBUCK; i += 256)
            part[b * NBUCK + i] = (u16)lh[i];
    }
}

// =====================================================================
// column scan: part[b][bkt] (u16) -> exclusive prefix over b (in place),
// tot[bkt] = column total.
// =====================================================================
__global__ __launch_bounds__(64) void kp_colscan(
    u16* __restrict__ part, unsigned int* __restrict__ tot)
{
    int bkt = blockIdx.x * 64 + threadIdx.x;   // 64 blocks x 64
    unsigned int run = 0;
#pragma unroll 8
    for (int k = 0; k < HBLOCKS; ++k) {
        unsigned int v = part[k * NBUCK + bkt];
        part[k * NBUCK + bkt] = (u16)run;
        run += v;
    }
    tot[bkt] = run;
}

// =====================================================================
// deterministic scatter: 256 blocks, LDS counters, no global atomics.
// =====================================================================
__global__ __launch_bounds__(256) void kp_scatter_det(
    const void* __restrict__ coords, const u16* __restrict__ part,
    const unsigned int* __restrict__ tot,
    int* __restrict__ order, int M)
{
    __shared__ unsigned int cnt[NBUCK];
    __shared__ unsigned int psum[256];
    int b = blockIdx.x;          // [0, 256)
    int t = threadIdx.x;
    unsigned int bs[16];
    unsigned int s = 0;
#pragma unroll
    for (int i = 0; i < 16; ++i) {
        bs[i] = tot[t * 16 + i];
        s += bs[i];
    }
    psum[t] = s;
    __syncthreads();
    if (t == 0) {
        unsigned int run = 0;
        for (int i = 0; i < 256; ++i) { unsigned int v = psum[i]; psum[i] = run; run += v; }
    }
    __syncthreads();
    unsigned int run = psum[t];
#pragma unroll
    for (int i = 0; i < 16; ++i) {
        int bkt = t * 16 + i;
        cnt[bkt] = run + (unsigned int)part[b * NBUCK + bkt];
        run += bs[i];
    }
    __syncthreads();
    int dt = detect_dt(coords);
    for (int p = b * 256 + t; p < M; p += HBLOCKS * 256) {
        int key = make_key(dt, coords, p);
        unsigned int pos = atomicAdd(&cnt[key], 1u);
        order[pos] = p;
    }
}

// =====================================================================
// shared math
// =====================================================================
struct Samp { int i0, i1; float w0, w1; };

static __device__ __forceinline__ Samp make_samp(float g, int N) {
    float ix = (g + 1.0f) * 0.5f * (float)(N - 1);
    float fl = floorf(ix);
    float w  = ix - fl;
    int i  = (int)fl;
    int i1 = i + 1;
    float v0 = (i  >= 0 && i  < N) ? 1.0f : 0.0f;
    float v1 = (i1 >= 0 && i1 < N) ? 1.0f : 0.0f;
    Samp s;
    s.w0 = (1.0f - w) * v0;
    s.w1 = w * v1;
    s.i0 = min(max(i, 0), N - 1);
    s.i1 = min(max(i1, 0), N - 1);
    return s;
}

#define MFMA16(a, b, c) __builtin_amdgcn_mfma_f32_16x16x32_f16((a), (b), (c), 0, 0, 0)

#define SRE 40
#define SR2 72

// one product term: interp -> LDS E (f16, relu'd) -> MFMA ta,tb -> feat += ta*tb
// NO barriers: single-wave in-order DS + per-lane aliasing keeps LDS order;
// global loads of later terms remain free to hoist above this term's MFMAs.
static __device__ __forceinline__ void term_mfma(
    int lane, const u16* __restrict__ Ls, const Samp& sl,
    const u16* __restrict__ Ps, const Samp& sa, const Samp& sb,
    const _Float16* __restrict__ Wt, const float* __restrict__ bvt,
    _Float16* El, _Float16* Ep, float (&feat)[4][2][4])
{
    int q = lane >> 4, l15 = lane & 15;
    const u16x8* l0  = (const u16x8*)(Ls + sl.i0 * 32);
    const u16x8* l1  = (const u16x8*)(Ls + sl.i1 * 32);
    const u16x8* p00 = (const u16x8*)(Ps + (sb.i0 * 128 + sa.i0) * 32);
    const u16x8* p01 = (const u16x8*)(Ps + (sb.i0 * 128 + sa.i1) * 32);
    const u16x8* p10 = (const u16x8*)(Ps + (sb.i1 * 128 + sa.i0) * 32);
    const u16x8* p11 = (const u16x8*)(Ps + (sb.i1 * 128 + sa.i1) * 32);
    float w00 = sb.w0 * sa.w0, w01 = sb.w0 * sa.w1;
    float w10 = sb.w1 * sa.w0, w11 = sb.w1 * sa.w1;
#pragma unroll
    for (int cc = 0; cc < 4; ++cc) {
        u16x8 A0 = l0[cc], A1 = l1[cc];
        u16x8 Q00 = p00[cc], Q01 = p01[cc], Q10 = p10[cc], Q11 = p11[cc];
        H8 hl, hp;
#pragma unroll
        for (int kk = 0; kk < 4; ++kk) {
            int k0 = 2 * kk, k1 = k0 + 1;
            float el0 = sl.w0 * bf2f(A0[k0]) + sl.w1 * bf2f(A1[k0]);
            float el1 = sl.w0 * bf2f(A0[k1]) + sl.w1 * bf2f(A1[k1]);
            float ep0 = w00 * bf2f(Q00[k0]) + w01 * bf2f(Q01[k0])
                      + w10 * bf2f(Q10[k0]) + w11 * bf2f(Q11[k0]);
            float ep1 = w00 * bf2f(Q00[k1]) + w01 * bf2f(Q01[k1])
                      + w10 * bf2f(Q10[k1]) + w11 * bf2f(Q11[k1]);
            hl.p[kk] = pk(fmaxf(el0, 0.0f), fmaxf(el1, 0.0f));
            hp.p[kk] = pk(fmaxf(ep0, 0.0f), fmaxf(ep1, 0.0f));
        }
        *(h8v*)&El[lane * SRE + cc * 8] = hl.v;
        *(h8v*)&Ep[lane * SRE + cc * 8] = hp.v;
    }
    h8v bf0 = *(const h8v*)&Wt[(l15) * 32 + q * 8];
    h8v bf1 = *(const h8v*)&Wt[(16 + l15) * 32 + q * 8];
    float bb0 = bvt[l15], bb1 = bvt[16 + l15];
    f4v c0 = {bb0, bb0, bb0, bb0};
    f4v c1 = {bb1, bb1, bb1, bb1};
#pragma unroll
    for (int mt = 0; mt < 4; ++mt) {
        h8v aL = *(const h8v*)&El[(mt * 16 + l15) * SRE + q * 8];
        h8v aP = *(const h8v*)&Ep[(mt * 16 + l15) * SRE + q * 8];
        f4v ta0 = MFMA16(aL, bf0, c0);
        f4v tb0 = MFMA16(aP, bf0, c0);
        f4v ta1 = MFMA16(aL, bf1, c1);
        f4v tb1 = MFMA16(aP, bf1, c1);
#pragma unroll
        for (int r = 0; r < 4; ++r) {
            feat[mt][0][r] += ta0[r] * tb0[r];
            feat[mt][1][r] += ta1[r] * tb1[r];
        }
    }
}

// =====================================================================
// MFMA main — single-wave blocks, barrier-free LDS, natural VGPR budget
// (NO min-waves launch-bound: R14's (64,4) forced VGPR=64 -> scratch
//  spills, WRITE_SIZE 16->108 MB, +45% time. Keep compiler's choice.)
// =====================================================================
__global__ __launch_bounds__(64) void kp_main_mfma(
    const void* __restrict__ coords, const int* __restrict__ order,
    const u16* __restrict__ planes_s, const u16* __restrict__ vol_s,
    const u16* __restrict__ lines_s,
    const float* __restrict__ wbase,
    void* __restrict__ out, int M)
{
    __shared__ _Float16 eb[5120];   // El[2560] | Ep[2560]; reused as E2[64*72=4608]
    int dt = detect_dt(coords);
    const _Float16* WtH = (const _Float16*)wbase;
    const float*    bv  = wbase + 1536;
    const _Float16* W1H = (const _Float16*)(wbase + 1632);
    const float*    b1v = wbase + 5728;
    const float*    W2v = wbase + 5856;
    const float*    b2v = wbase + 5984;

    int lane = threadIdx.x;
    int q = lane >> 4, l15 = lane & 15;
    _Float16* El = eb;
    _Float16* Ep = eb + 2560;
    _Float16* E2 = eb;
    float* res = (float*)(eb + 4608);   // 64 floats in E2's unused tail

    int p = blockIdx.x * 64 + lane;
    p = min(p, M - 1);
    int sp = order[p];

    float x = gld(dt, coords, sp * 3 + 0);
    float y = gld(dt, coords, sp * 3 + 1);
    float z = gld(dt, coords, sp * 3 + 2);

    Samp sx = make_samp(x, 128), sy = make_samp(y, 128), sz = make_samp(z, 128);

    float feat[4][2][4];
#pragma unroll
    for (int mt = 0; mt < 4; ++mt)
#pragma unroll
        for (int n = 0; n < 2; ++n)
#pragma unroll
            for (int r = 0; r < 4; ++r) feat[mt][n][r] = 0.0f;

    term_mfma(lane, lines_s + 0 * 4096, sx, planes_s + 1 * 524288, sy, sz,
              WtH + 0,    bv + 0,  El, Ep, feat);
    term_mfma(lane, lines_s + 1 * 4096, sy, planes_s + 2 * 524288, sx, sz,
              WtH + 1024, bv + 32, El, Ep, feat);
    term_mfma(lane, lines_s + 2 * 4096, sz, planes_s + 0 * 524288, sx, sy,
              WtH + 2048, bv + 64, El, Ep, feat);

    CBAR();   // El/Ep -> E2 buffer reuse: forbid compiler proving disjointness

#pragma unroll
    for (int mt = 0; mt < 4; ++mt)
#pragma unroll
        for (int n = 0; n < 2; ++n)
#pragma unroll
            for (int r = 0; r < 4; ++r)
                E2[(mt * 16 + q * 4 + r) * SR2 + n * 16 + l15] =
                    (_Float16)feat[mt][n][r];
    {
        Samp vx = make_samp(x, 64), vy = make_samp(y, 64), vz = make_samp(z, 64);
        float vf[8];
#pragma unroll
        for (int c = 0; c < 8; ++c) vf[c] = 0.0f;
#pragma unroll
        for (int corner = 0; corner < 8; ++corner) {
            int dx = corner & 1, dy = (corner >> 1) & 1, dz = corner >> 2;
            int xi = dx ? vx.i1 : vx.i0;
            int yi = dy ? vy.i1 : vy.i0;
            int zi = dz ? vz.i1 : vz.i0;
            float w = (dx ? vx.w1 : vx.w0) * (dy ? vy.w1 : vy.w0) * (dz ? vz.w1 : vz.w0);
            u16x8 v = *(const u16x8*)(vol_s + (((zi * 64) + yi) * 64 + xi) * 8);
#pragma unroll
            for (int c = 0; c < 8; ++c)
                vf[c] = fmaf(w, bf2f(v[c]), vf[c]);
        }
        H8 hv;
#pragma unroll
        for (int k = 0; k < 4; ++k) hv.p[k] = pk(vf[2 * k], vf[2 * k + 1]);
        *(h8v*)&E2[lane * SR2 + 32] = hv.v;
        h8v zz = {};
        *(h8v*)&E2[lane * SR2 + 40] = zz;
        *(h8v*)&E2[lane * SR2 + 48] = zz;
        *(h8v*)&E2[lane * SR2 + 56] = zz;
    }
    CBAR();

    h8v af[4][2];
#pragma unroll
    for (int mt = 0; mt < 4; ++mt)
#pragma unroll
        for (int ks = 0; ks < 2; ++ks)
            af[mt][ks] = *(const h8v*)&E2[(mt * 16 + l15) * SR2 + ks * 32 + q * 8];

    float s[4][4];
#pragma unroll
    for (int mt = 0; mt < 4; ++mt)
#pragma unroll
        for (int r = 0; r < 4; ++r) s[mt][r] = 0.0f;

#pragma unroll
    for (int NT = 0; NT < 8; ++NT) {
        int o = NT * 16 + l15;
        h8v b0 = *(const h8v*)&W1H[o * 64 + q * 8];
        h8v b1f = *(const h8v*)&W1H[o * 64 + 32 + q * 8];
        float w2 = W2v[o];
        float bb = b1v[o];
        f4v cinit = {bb, bb, bb, bb};
#pragma unroll
        for (int mt = 0; mt < 4; ++mt) {
            f4v c = MFMA16(af[mt][0], b0, cinit);
            c = MFMA16(af[mt][1], b1f, c);
#pragma unroll
            for (int r = 0; r < 4; ++r)
                s[mt][r] = fmaf(fmaxf(c[r], 0.0f), w2, s[mt][r]);
        }
    }
#pragma unroll
    for (int mt = 0; mt < 4; ++mt)
#pragma unroll
        for (int r = 0; r < 4; ++r) {
            float v = s[mt][r];
            v += __shfl_xor(v, 1);
            v += __shfl_xor(v, 2);
            v += __shfl_xor(v, 4);
            v += __shfl_xor(v, 8);
            s[mt][r] = v;
        }
    CBAR();   // res overlaps E2 tail (disjoint, but keep order pinned)
    if (l15 == 0) {
#pragma unroll
        for (int mt = 0; mt < 4; ++mt)
#pragma unroll
            for (int r = 0; r < 4; ++r)
                res[mt * 16 + q * 4 + r] = s[mt][r];
    }
    CBAR();
    float rr = res[lane] + b2v[0];
    if (dt) ((float*)out)[sp] = rr;
    else    ((u16*)out)[sp] = f2bf(rr);
}

// =====================================================================
// fallback path (ws too small): weights-only prep + direct gathers
// =====================================================================
__global__ void kp_prep_weights_fb(
    const void* __restrict__ coords,
    const void* __restrict__ Wx, const void* __restrict__ bx,
    const void* __restrict__ Wy, const void* __restrict__ by,
    const void* __restrict__ Wz, const void* __restrict__ bz,
    const void* __restrict__ W1, const void* __restrict__ b1,
    const void* __restrict__ W2, const void* __restrict__ b2,
    float* __restrict__ wbase)
{
    int dt = detect_dt(coords);
    int t = blockIdx.x * blockDim.x + threadIdx.x;
    weights_work(dt, t, Wx, bx, Wy, by, Wz, bz, W1, b1, W2, b2, wbase);
}

__global__ __launch_bounds__(256) void kp_main_direct(
    const void* __restrict__ coords,
    const void* __restrict__ lx, const void* __restrict__ ly, const void* __restrict__ lz,
    const void* __restrict__ pxy, const void* __restrict__ pyz, const void* __restrict__ pxz,
    const void* __restrict__ vol,
    const float* __restrict__ wbase,
    void* __restrict__ out, int M)
{
    int dt = detect_dt(coords);
    const _Float16* WtH = (const _Float16*)wbase;
    const float*    bv  = wbase + 1536;
    const _Float16* W1H = (const _Float16*)(wbase + 1632);
    const float*    b1v = wbase + 5728;
    const float*    W2v = wbase + 5856;
    const float*    b2v = wbase + 5984;

    int p = blockIdx.x * 256 + threadIdx.x;
    p = min(p, M - 1);

    float x = gld(dt, coords, p * 3 + 0);
    float y = gld(dt, coords, p * 3 + 1);
    float z = gld(dt, coords, p * 3 + 2);

    Samp sx = make_samp(x, 128), sy = make_samp(y, 128), sz = make_samp(z, 128);

    float feat[40];
#pragma unroll
    for (int o = 0; o < 40; ++o) feat[o] = 0.0f;

    const void* Ls[3] = {lx, ly, lz};
    const void* Psv[3] = {pyz, pxz, pxy};
    Samp sl3[3] = {sx, sy, sz};
    Samp sa3[3] = {sy, sx, sx};
    Samp sb3[3] = {sz, sz, sy};
#pragma unroll 1
    for (int m = 0; m < 3; ++m) {
        float ta[32], tb[32];
        const float* bvt = bv + m * 32;
        const _Float16* Wt = WtH + m * 1024;
#pragma unroll
        for (int o = 0; o < 32; ++o) { ta[o] = bvt[o]; tb[o] = bvt[o]; }
        Samp sl = sl3[m], sa = sa3[m], sb = sb3[m];
        float w00 = sb.w0 * sa.w0, w01 = sb.w0 * sa.w1;
        float w10 = sb.w1 * sa.w0, w11 = sb.w1 * sa.w1;
        int i00 = sb.i0 * 128 + sa.i0, i01 = sb.i0 * 128 + sa.i1;
        int i10 = sb.i1 * 128 + sa.i0, i11 = sb.i1 * 128 + sa.i1;
#pragma unroll 1
        for (int c = 0; c < 32; ++c) {
            float el = sl.w0 * gld(dt, Ls[m], c * 128 + sl.i0)
                     + sl.w1 * gld(dt, Ls[m], c * 128 + sl.i1);
            float ep = w00 * gld(dt, Psv[m], c * 16384 + i00)
                     + w01 * gld(dt, Psv[m], c * 16384 + i01)
                     + w10 * gld(dt, Psv[m], c * 16384 + i10)
                     + w11 * gld(dt, Psv[m], c * 16384 + i11);
            float r1 = fmaxf(el, 0.0f), r2 = fmaxf(ep, 0.0f);
#pragma unroll
            for (int o = 0; o < 32; ++o) {
                float w = (float)Wt[o * 32 + c];
                ta[o] = fmaf(r1, w, ta[o]);
                tb[o] = fmaf(r2, w, tb[o]);
            }
        }
#pragma unroll
        for (int o = 0; o < 32; ++o) feat[o] = fmaf(ta[o], tb[o], feat[o]);
    }

    Samp vx = make_samp(x, 64), vy = make_samp(y, 64), vz = make_samp(z, 64);
#pragma unroll 1
    for (int corner = 0; corner < 8; ++corner) {
        int dx = corner & 1, dy = (corner >> 1) & 1, dz = corner >> 2;
        int xi = dx ? vx.i1 : vx.i0;
        int yi = dy ? vy.i1 : vy.i0;
        int zi = dz ? vz.i1 : vz.i0;
        float w = (dx ? vx.w1 : vx.w0) * (dy ? vy.w1 : vy.w0) * (dz ? vz.w1 : vz.w0);
        int pos = ((zi * 64) + yi) * 64 + xi;
#pragma unroll
        for (int c = 0; c < 8; ++c)
            feat[32 + c] = fmaf(w, gld(dt, vol, c * 262144 + pos), feat[32 + c]);
    }

    float acc_out = b2v[0];
#pragma unroll 2
    for (int j = 0; j < 128; ++j) {
        float acc = b1v[j];
        const _Float16* wr = W1H + j * 64;
#pragma unroll
        for (int i = 0; i < 40; ++i)
            acc = fmaf(feat[i], (float)wr[i], acc);
        acc_out = fmaf(fmaxf(acc, 0.0f), W2v[j], acc_out);
    }
    if (dt) ((float*)out)[p] = acc_out;
    else    ((u16*)out)[p] = f2bf(acc_out);
}

// =====================================================================
extern "C" void kernel_launch(void* const* d_in, const int* in_sizes, int n_in,
                              void* d_out, int out_size, void* d_ws, size_t ws_size,
                              hipStream_t stream) {
    const void* coords = d_in[0];
    const void* lx  = d_in[1];
    const void* ly  = d_in[2];
    const void* lz  = d_in[3];
    const void* pxy = d_in[4];
    const void* pyz = d_in[5];
    const void* pxz = d_in[6];
    const void* vol = d_in[7];
    const void* Wx  = d_in[8];
    const void* bx  = d_in[9];
    const void* Wy  = d_in[10];
    const void* by  = d_in[11];
    const void* Wz  = d_in[12];
    const void* bz  = d_in[13];
    const void* W1  = d_in[14];
    const void* b1  = d_in[15];
    const void* W2  = d_in[16];
    const void* b2  = d_in[17];

    int M = in_sizes[0] / 3;

    char* ws = (char*)d_ws;
    float*        wbase    = (float*)(ws + WF_OFF);
    u16*          planes_s = (u16*)(ws + PLANES_S_OFF);
    u16*          vol_s    = (u16*)(ws + VOL_S_OFF);
    u16*          lines_s  = (u16*)(ws + LINES_S_OFF);
    u16*          part     = (u16*)(ws + PART_OFF);
    unsigned int* tot      = (unsigned int*)(ws + TOT_OFF);
    int*          order    = (int*)(ws + ORDER_OFF);

    size_t need_sorted = (size_t)ORDER_OFF + (size_t)M * 4u;

    if (ws_size >= need_sorted) {
        kp_prep_all<<<2100, 256, 0, stream>>>(coords, lx, ly, lz, pxy, pyz, pxz, vol,
                                              Wx, bx, Wy, by, Wz, bz, W1, b1, W2, b2,
                                              wbase, planes_s, vol_s, lines_s, part, M);
        kp_colscan<<<64, 64, 0, stream>>>(part, tot);
        kp_scatter_det<<<HBLOCKS, 256, 0, stream>>>(coords, part, tot, order, M);
        int blocks64 = (M + 63) / 64;
        kp_main_mfma<<<blocks64, 64, 0, stream>>>(coords, order,
                                                  planes_s, vol_s,
                                                  lines_s, wbase, d_out, M);
    } else {
        int blocks = (M + 255) / 256;
        kp_prep_weights_fb<<<46, 256, 0, stream>>>(coords, Wx, bx, Wy, by, Wz, bz,
                                                   W1, b1, W2, b2, wbase);
        kp_main_direct<<<blocks, 256, 0, stream>>>(coords, lx, ly, lz, pxy, pyz, pxz,
                                                   vol, wbase, d_out, M);
    }
}

// Round 16
// 200.362 us; speedup vs baseline: 1.1382x; 1.0077x over previous
//
#include <hip/hip_runtime.h>

typedef unsigned short u16;
typedef u16 u16x8 __attribute__((ext_vector_type(8)));
typedef _Float16 half2 __attribute__((ext_vector_type(2)));
typedef _Float16 h8v __attribute__((ext_vector_type(8)));
typedef float f4v __attribute__((ext_vector_type(4)));

union H8 { h8v v; half2 p[4]; };

// ---------- bf16 helpers ----------
static __device__ __forceinline__ float bf2f(u16 u) {
    union { unsigned int i; float f; } v;
    v.i = ((unsigned int)u) << 16;
    return v.f;
}
static __device__ __forceinline__ u16 f2bf(float f) {
    union { float f; unsigned int i; } v;
    v.f = f;
    unsigned int x = v.i;
    x += 0x7fffu + ((x >> 16) & 1u);   // RNE
    return (u16)(x >> 16);
}
static __device__ __forceinline__ float gld(int dt, const void* p, int i) {
    return dt ? ((const float*)p)[i] : bf2f(((const u16*)p)[i]);
}
static __device__ __forceinline__ int detect_dt(const void* coords) {
    u16 v = ((const u16*)coords)[threadIdx.x & 63];
    int e = (v >> 7) & 0xFF;
    bool inr = (e >= 90) && (e <= 126);
    unsigned long long m = __ballot(inr);
    return (__popcll(m) >= 56) ? 0 : 1;   // 0=bf16, 1=f32
}
static __device__ __forceinline__ half2 pk(float a, float b) {
    return __builtin_bit_cast(half2, __builtin_amdgcn_cvt_pkrtz(a, b));
}

// compiler-reordering barrier only (no instructions emitted); single-wave
// workgroups keep LDS order in HW (in-order DS + per-lane aliasing).
#define CBAR() asm volatile("" ::: "memory")

// ---------- ws layout (bytes) ----------
#define WF_OFF        64u
#define PLANES_S_OFF  34304u         // 3*524288 u16
#define VOL_S_OFF     3180032u       // 2097152 u16
#define LINES_S_OFF   7374336u       // 12288 u16
#define PART_OFF      7398912u       // 256*4096 u16 = 2 MB
#define TOT_OFF       9496064u       // 4096 u32
#define ORDER_OFF     9512448u       // 4*M
// SCOORD_OFF = ORDER_OFF + 4*M (runtime), 6*M bytes (u16 x3)

#define NBUCK 4096
#define HBLOCKS 256

// weight region (float units from wbase):
//   Wt  f16[3][32 o][32 c]   | bv f32[96] | W1t f16[128][64 pad]
//   b1v f32[128] | W2v f32[128] | b2v f32[1]

// =====================================================================
// spatial key
// =====================================================================
static __device__ __forceinline__ int make_key3(float x, float y, float z) {
    int kx = min(max((int)((x + 1.0f) * 8.0f), 0), 15);
    int ky = min(max((int)((y + 1.0f) * 8.0f), 0), 15);
    int kz = min(max((int)((z + 1.0f) * 8.0f), 0), 15);
    return (kz * 16 + ky) * 16 + kx;
}
static __device__ __forceinline__ int make_key(int dt, const void* coords, int p) {
    return make_key3(gld(dt, coords, p * 3 + 0), gld(dt, coords, p * 3 + 1),
                     gld(dt, coords, p * 3 + 2));
}

// =====================================================================
// weight packing (f16 MFMA layouts)
// =====================================================================
static __device__ __forceinline__ void weights_work(
    int dt, int r,
    const void* Wx, const void* bx, const void* Wy, const void* by,
    const void* Wz, const void* bz, const void* W1, const void* b1,
    const void* W2, const void* b2, float* wbase)
{
    _Float16* WtH = (_Float16*)wbase;
    float*    bv  = wbase + 1536;
    _Float16* W1H = (_Float16*)(wbase + 1632);
    float*    b1v = wbase + 5728;
    float*    W2v = wbase + 5856;
    float*    b2v = wbase + 5984;
    if (r < 3072) {
        int m = r >> 10, idx = r & 1023;
        int o = idx >> 5, c = idx & 31;
        const void* s = (m == 0) ? Wx : (m == 1) ? Wy : Wz;
        WtH[r] = (_Float16)gld(dt, s, c * 32 + o);   // Wt[m][o][c] = W[c][o]
    } else if (r < 3168) {
        int q2 = r - 3072;
        int m = q2 >> 5, c = q2 & 31;
        const void* s = (m == 0) ? bx : (m == 1) ? by : bz;
        bv[q2] = gld(dt, s, c);
    } else if (r < 11360) {
        int idx = r - 3168;                 // j*64 + i
        int j = idx >> 6, i = idx & 63;
        W1H[idx] = (i < 40) ? (_Float16)gld(dt, W1, i * 128 + j) : (_Float16)0.0f;
    } else if (r < 11488) {
        b1v[r - 11360] = gld(dt, b1, r - 11360);
    } else if (r < 11616) {
        W2v[r - 11488] = gld(dt, W2, r - 11488);
    } else if (r == 11616) {
        b2v[0] = gld(dt, b2, 0);
    }
}

// =====================================================================
// fused prep: grid transpose (0..1797) + weights (1798..1843)
//           + histogram partials u16, plain stores (1844..2099)
// =====================================================================
__global__ __launch_bounds__(256) void kp_prep_all(
    const void* __restrict__ coords,
    const void* __restrict__ lx, const void* __restrict__ ly,
    const void* __restrict__ lz,
    const void* __restrict__ pxy, const void* __restrict__ pyz,
    const void* __restrict__ pxz, const void* __restrict__ vol,
    const void* __restrict__ Wx, const void* __restrict__ bx,
    const void* __restrict__ Wy, const void* __restrict__ by,
    const void* __restrict__ Wz, const void* __restrict__ bz,
    const void* __restrict__ W1, const void* __restrict__ b1,
    const void* __restrict__ W2, const void* __restrict__ b2,
    float* __restrict__ wbase,
    u16* __restrict__ planes_s, u16* __restrict__ vol_s,
    u16* __restrict__ lines_s, u16* __restrict__ part, int M)
{
    __shared__ unsigned int lh[NBUCK];
    int dt = detect_dt(coords);
    int blk = blockIdx.x;
    if (blk < 1798) {
        int t = blk * 256 + threadIdx.x;   // [0, 460288)
        u16x8 v;
        if (t < 196608) {                 // planes: 8 consecutive out u16
            int o = t * 8;
            int pl = o >> 19;
            int r  = o & 524287;
            int pos = r >> 5, c0 = r & 31;
            const void* src = (pl == 0) ? pxy : (pl == 1) ? pyz : pxz;
#pragma unroll
            for (int i = 0; i < 8; ++i)
                v[i] = dt ? f2bf(((const float*)src)[(c0 + i) * 16384 + pos])
                          : ((const u16*)src)[(c0 + i) * 16384 + pos];
            *(u16x8*)(planes_s + o) = v;
        } else if (t < 458752) {          // volume: thread = one pos, 8 channels
            int pos = t - 196608;
#pragma unroll
            for (int c = 0; c < 8; ++c)
                v[c] = dt ? f2bf(((const float*)vol)[c * 262144 + pos])
                          : ((const u16*)vol)[c * 262144 + pos];
            *(u16x8*)(vol_s + pos * 8) = v;
        } else {                          // lines
            int o = (t - 458752) * 8;
            int l = o >> 12, rr = o & 4095;
            int pos = rr >> 5, c0 = rr & 31;
            const void* src = (l == 0) ? lx : (l == 1) ? ly : lz;
#pragma unroll
            for (int i = 0; i < 8; ++i)
                v[i] = dt ? f2bf(((const float*)src)[(c0 + i) * 128 + pos])
                          : ((const u16*)src)[(c0 + i) * 128 + pos];
            *(u16x8*)(lines_s + o) = v;
        }
    } else if (blk < 1844) {
        int r = (blk - 1798) * 256 + threadIdx.x;   // [0, 11776)
        weights_work(dt, r, Wx, bx, Wy, by, Wz, bz, W1, b1, W2, b2, wbase);
    } else {
        int b = blk - 1844;               // [0, 256)
        for (int i = threadIdx.x; i < NBUCK; i += 256) lh[i] = 0u;
        __syncthreads();
        for (int p = b * 256 + threadIdx.x; p < M; p += HBLOCKS * 256)
            atomicAdd(&lh[make_key(dt, coords, p)], 1u);
        __syncthreads();
        for (int i = threadIdx.x; i < NBUCK; i += 256)
            part[b * NBUCK + i] = (u16)lh[i];
    }
}

// =====================================================================
// column scan: part[b][bkt] (u16) -> exclusive prefix over b (in place),
// tot[bkt] = column total.
// =====================================================================
__global__ __launch_bounds__(64) void kp_colscan(
    u16* __restrict__ part, unsigned int* __restrict__ tot)
{
    int bkt = blockIdx.x * 64 + threadIdx.x;   // 64 blocks x 64
    unsigned int run = 0;
#pragma unroll 8
    for (int k = 0; k < HBLOCKS; ++k) {
        unsigned int v = part[k * NBUCK + bkt];
        part[k * NBUCK + bkt] = (u16)run;
        run += v;
    }
    tot[bkt] = run;
}

// =====================================================================
// deterministic scatter: 256 blocks, LDS counters, no global atomics.
// Emits reordered raw-bf16 coords (dt==0) so main reads them coalesced
// (removes the random coords gather from main's critical path).
// =====================================================================
__global__ __launch_bounds__(256) void kp_scatter_det(
    const void* __restrict__ coords, const u16* __restrict__ part,
    const unsigned int* __restrict__ tot,
    int* __restrict__ order, u16* __restrict__ scoords, int M)
{
    __shared__ unsigned int cnt[NBUCK];
    __shared__ unsigned int psum[256];
    int b = blockIdx.x;          // [0, 256)
    int t = threadIdx.x;
    unsigned int bs[16];
    unsigned int s = 0;
#pragma unroll
    for (int i = 0; i < 16; ++i) {
        bs[i] = tot[t * 16 + i];
        s += bs[i];
    }
    psum[t] = s;
    __syncthreads();
    if (t == 0) {
        unsigned int run = 0;
        for (int i = 0; i < 256; ++i) { unsigned int v = psum[i]; psum[i] = run; run += v; }
    }
    __syncthreads();
    unsigned int run = psum[t];
#pragma unroll
    for (int i = 0; i < 16; ++i) {
        int bkt = t * 16 + i;
        cnt[bkt] = run + (unsigned int)part[b * NBUCK + bkt];
        run += bs[i];
    }
    __syncthreads();
    int dt = detect_dt(coords);
    const u16* cu = (const u16*)coords;
    for (int p = b * 256 + t; p < M; p += HBLOCKS * 256) {
        float x = gld(dt, coords, p * 3 + 0);
        float y = gld(dt, coords, p * 3 + 1);
        float z = gld(dt, coords, p * 3 + 2);
        int key = make_key3(x, y, z);
        unsigned int pos = atomicAdd(&cnt[key], 1u);
        order[pos] = p;
        if (dt == 0) {
            scoords[pos * 3 + 0] = cu[p * 3 + 0];
            scoords[pos * 3 + 1] = cu[p * 3 + 1];
            scoords[pos * 3 + 2] = cu[p * 3 + 2];
        }
    }
}

// =====================================================================
// shared math
// =====================================================================
struct Samp { int i0, i1; float w0, w1; };

static __device__ __forceinline__ Samp make_samp(float g, int N) {
    float ix = (g + 1.0f) * 0.5f * (float)(N - 1);
    float fl = floorf(ix);
    float w  = ix - fl;
    int i  = (int)fl;
    int i1 = i + 1;
    float v0 = (i  >= 0 && i  < N) ? 1.0f : 0.0f;
    float v1 = (i1 >= 0 && i1 < N) ? 1.0f : 0.0f;
    Samp s;
    s.w0 = (1.0f - w) * v0;
    s.w1 = w * v1;
    s.i0 = min(max(i, 0), N - 1);
    s.i1 = min(max(i1, 0), N - 1);
    return s;
}

#define MFMA16(a, b, c) __builtin_amdgcn_mfma_f32_16x16x32_f16((a), (b), (c), 0, 0, 0)

#define SRE 40
#define SR2 72

// one product term: interp -> LDS E (f16, relu'd) -> MFMA ta,tb -> feat += ta*tb
static __device__ __forceinline__ void term_mfma(
    int lane, const u16* __restrict__ Ls, const Samp& sl,
    const u16* __restrict__ Ps, const Samp& sa, const Samp& sb,
    const _Float16* __restrict__ Wt, const float* __restrict__ bvt,
    _Float16* El, _Float16* Ep, float (&feat)[4][2][4])
{
    int q = lane >> 4, l15 = lane & 15;
    const u16x8* l0  = (const u16x8*)(Ls + sl.i0 * 32);
    const u16x8* l1  = (const u16x8*)(Ls + sl.i1 * 32);
    const u16x8* p00 = (const u16x8*)(Ps + (sb.i0 * 128 + sa.i0) * 32);
    const u16x8* p01 = (const u16x8*)(Ps + (sb.i0 * 128 + sa.i1) * 32);
    const u16x8* p10 = (const u16x8*)(Ps + (sb.i1 * 128 + sa.i0) * 32);
    const u16x8* p11 = (const u16x8*)(Ps + (sb.i1 * 128 + sa.i1) * 32);
    float w00 = sb.w0 * sa.w0, w01 = sb.w0 * sa.w1;
    float w10 = sb.w1 * sa.w0, w11 = sb.w1 * sa.w1;
#pragma unroll
    for (int cc = 0; cc < 4; ++cc) {
        u16x8 A0 = l0[cc], A1 = l1[cc];
        u16x8 Q00 = p00[cc], Q01 = p01[cc], Q10 = p10[cc], Q11 = p11[cc];
        H8 hl, hp;
#pragma unroll
        for (int kk = 0; kk < 4; ++kk) {
            int k0 = 2 * kk, k1 = k0 + 1;
            float el0 = sl.w0 * bf2f(A0[k0]) + sl.w1 * bf2f(A1[k0]);
            float el1 = sl.w0 * bf2f(A0[k1]) + sl.w1 * bf2f(A1[k1]);
            float ep0 = w00 * bf2f(Q00[k0]) + w01 * bf2f(Q01[k0])
                      + w10 * bf2f(Q10[k0]) + w11 * bf2f(Q11[k0]);
            float ep1 = w00 * bf2f(Q00[k1]) + w01 * bf2f(Q01[k1])
                      + w10 * bf2f(Q10[k1]) + w11 * bf2f(Q11[k1]);
            hl.p[kk] = pk(fmaxf(el0, 0.0f), fmaxf(el1, 0.0f));
            hp.p[kk] = pk(fmaxf(ep0, 0.0f), fmaxf(ep1, 0.0f));
        }
        *(h8v*)&El[lane * SRE + cc * 8] = hl.v;
        *(h8v*)&Ep[lane * SRE + cc * 8] = hp.v;
    }
    h8v bf0 = *(const h8v*)&Wt[(l15) * 32 + q * 8];
    h8v bf1 = *(const h8v*)&Wt[(16 + l15) * 32 + q * 8];
    float bb0 = bvt[l15], bb1 = bvt[16 + l15];
    f4v c0 = {bb0, bb0, bb0, bb0};
    f4v c1 = {bb1, bb1, bb1, bb1};
#pragma unroll
    for (int mt = 0; mt < 4; ++mt) {
        h8v aL = *(const h8v*)&El[(mt * 16 + l15) * SRE + q * 8];
        h8v aP = *(const h8v*)&Ep[(mt * 16 + l15) * SRE + q * 8];
        f4v ta0 = MFMA16(aL, bf0, c0);
        f4v tb0 = MFMA16(aP, bf0, c0);
        f4v ta1 = MFMA16(aL, bf1, c1);
        f4v tb1 = MFMA16(aP, bf1, c1);
#pragma unroll
        for (int r = 0; r < 4; ++r) {
            feat[mt][0][r] += ta0[r] * tb0[r];
            feat[mt][1][r] += ta1[r] * tb1[r];
        }
    }
}

// =====================================================================
// MFMA main — single-wave blocks, barrier-free LDS, coalesced scoords
// =====================================================================
__global__ __launch_bounds__(64) void kp_main_mfma(
    const void* __restrict__ coords, const int* __restrict__ order,
    const u16* __restrict__ scoords,
    const u16* __restrict__ planes_s, const u16* __restrict__ vol_s,
    const u16* __restrict__ lines_s,
    const float* __restrict__ wbase,
    void* __restrict__ out, int M)
{
    __shared__ _Float16 eb[5120];   // El[2560] | Ep[2560]; reused as E2[64*72=4608]
    int dt = detect_dt(coords);
    const _Float16* WtH = (const _Float16*)wbase;
    const float*    bv  = wbase + 1536;
    const _Float16* W1H = (const _Float16*)(wbase + 1632);
    const float*    b1v = wbase + 5728;
    const float*    W2v = wbase + 5856;
    const float*    b2v = wbase + 5984;

    int lane = threadIdx.x;
    int q = lane >> 4, l15 = lane & 15;
    _Float16* El = eb;
    _Float16* Ep = eb + 2560;
    _Float16* E2 = eb;
    float* res = (float*)(eb + 4608);   // 64 floats in E2's unused tail

    int p = blockIdx.x * 64 + lane;
    p = min(p, M - 1);
    int sp = order[p];

    float x, y, z;
    if (dt == 0) {
        x = bf2f(scoords[p * 3 + 0]);
        y = bf2f(scoords[p * 3 + 1]);
        z = bf2f(scoords[p * 3 + 2]);
    } else {
        x = ((const float*)coords)[sp * 3 + 0];
        y = ((const float*)coords)[sp * 3 + 1];
        z = ((const float*)coords)[sp * 3 + 2];
    }

    Samp sx = make_samp(x, 128), sy = make_samp(y, 128), sz = make_samp(z, 128);

    float feat[4][2][4];
#pragma unroll
    for (int mt = 0; mt < 4; ++mt)
#pragma unroll
        for (int n = 0; n < 2; ++n)
#pragma unroll
            for (int r = 0; r < 4; ++r) feat[mt][n][r] = 0.0f;

    term_mfma(lane, lines_s + 0 * 4096, sx, planes_s + 1 * 524288, sy, sz,
              WtH + 0,    bv + 0,  El, Ep, feat);
    term_mfma(lane, lines_s + 1 * 4096, sy, planes_s + 2 * 524288, sx, sz,
              WtH + 1024, bv + 32, El, Ep, feat);
    term_mfma(lane, lines_s + 2 * 4096, sz, planes_s + 0 * 524288, sx, sy,
              WtH + 2048, bv + 64, El, Ep, feat);

    CBAR();   // El/Ep -> E2 buffer reuse: forbid compiler proving disjointness

#pragma unroll
    for (int mt = 0; mt < 4; ++mt)
#pragma unroll
        for (int n = 0; n < 2; ++n)
#pragma unroll
            for (int r = 0; r < 4; ++r)
                E2[(mt * 16 + q * 4 + r) * SR2 + n * 16 + l15] =
                    (_Float16)feat[mt][n][r];
    {
        Samp vx = make_samp(x, 64), vy = make_samp(y, 64), vz = make_samp(z, 64);
        float vf[8];
#pragma unroll
        for (int c = 0; c < 8; ++c) vf[c] = 0.0f;
#pragma unroll
        for (int corner = 0; corner < 8; ++corner) {
            int dx = corner & 1, dy = (corner >> 1) & 1, dz = corner >> 2;
            int xi = dx ? vx.i1 : vx.i0;
            int yi = dy ? vy.i1 : vy.i0;
            int zi = dz ? vz.i1 : vz.i0;
            float w = (dx ? vx.w1 : vx.w0) * (dy ? vy.w1 : vy.w0) * (dz ? vz.w1 : vz.w0);
            u16x8 v = *(const u16x8*)(vol_s + (((zi * 64) + yi) * 64 + xi) * 8);
#pragma unroll
            for (int c = 0; c < 8; ++c)
                vf[c] = fmaf(w, bf2f(v[c]), vf[c]);
        }
        H8 hv;
#pragma unroll
        for (int k = 0; k < 4; ++k) hv.p[k] = pk(vf[2 * k], vf[2 * k + 1]);
        *(h8v*)&E2[lane * SR2 + 32] = hv.v;
        h8v zz = {};
        *(h8v*)&E2[lane * SR2 + 40] = zz;
        *(h8v*)&E2[lane * SR2 + 48] = zz;
        *(h8v*)&E2[lane * SR2 + 56] = zz;
    }
    CBAR();

    h8v af[4][2];
#pragma unroll
    for (int mt = 0; mt < 4; ++mt)
#pragma unroll
        for (int ks = 0; ks < 2; ++ks)
            af[mt][ks] = *(const h8v*)&E2[(mt * 16 + l15) * SR2 + ks * 32 + q * 8];

    float s[4][4];
#pragma unroll
    for (int mt = 0; mt < 4; ++mt)
#pragma unroll
        for (int r = 0; r < 4; ++r) s[mt][r] = 0.0f;

#pragma unroll
    for (int NT = 0; NT < 8; ++NT) {
        int o = NT * 16 + l15;
        h8v b0 = *(const h8v*)&W1H[o * 64 + q * 8];
        h8v b1f = *(const h8v*)&W1H[o * 64 + 32 + q * 8];
        float w2 = W2v[o];
        float bb = b1v[o];
        f4v cinit = {bb, bb, bb, bb};
#pragma unroll
        for (int mt = 0; mt < 4; ++mt) {
            f4v c = MFMA16(af[mt][0], b0, cinit);
            c = MFMA16(af[mt][1], b1f, c);
#pragma unroll
            for (int r = 0; r < 4; ++r)
                s[mt][r] = fmaf(fmaxf(c[r], 0.0f), w2, s[mt][r]);
        }
    }
#pragma unroll
    for (int mt = 0; mt < 4; ++mt)
#pragma unroll
        for (int r = 0; r < 4; ++r) {
            float v = s[mt][r];
            v += __shfl_xor(v, 1);
            v += __shfl_xor(v, 2);
            v += __shfl_xor(v, 4);
            v += __shfl_xor(v, 8);
            s[mt][r] = v;
        }
    CBAR();   // res overlaps E2 tail (disjoint, but keep order pinned)
    if (l15 == 0) {
#pragma unroll
        for (int mt = 0; mt < 4; ++mt)
#pragma unroll
            for (int r = 0; r < 4; ++r)
                res[mt * 16 + q * 4 + r] = s[mt][r];
    }
    CBAR();
    float rr = res[lane] + b2v[0];
    if (dt) ((float*)out)[sp] = rr;
    else    ((u16*)out)[sp] = f2bf(rr);
}

// =====================================================================
// fallback path (ws too small): weights-only prep + direct gathers
// =====================================================================
__global__ void kp_prep_weights_fb(
    const void* __restrict__ coords,
    const void* __restrict__ Wx, const void* __restrict__ bx,
    const void* __restrict__ Wy, const void* __restrict__ by,
    const void* __restrict__ Wz, const void* __restrict__ bz,
    const void* __restrict__ W1, const void* __restrict__ b1,
    const void* __restrict__ W2, const void* __restrict__ b2,
    float* __restrict__ wbase)
{
    int dt = detect_dt(coords);
    int t = blockIdx.x * blockDim.x + threadIdx.x;
    weights_work(dt, t, Wx, bx, Wy, by, Wz, bz, W1, b1, W2, b2, wbase);
}

__global__ __launch_bounds__(256) void kp_main_direct(
    const void* __restrict__ coords,
    const void* __restrict__ lx, const void* __restrict__ ly, const void* __restrict__ lz,
    const void* __restrict__ pxy, const void* __restrict__ pyz, const void* __restrict__ pxz,
    const void* __restrict__ vol,
    const float* __restrict__ wbase,
    void* __restrict__ out, int M)
{
    int dt = detect_dt(coords);
    const _Float16* WtH = (const _Float16*)wbase;
    const float*    bv  = wbase + 1536;
    const _Float16* W1H = (const _Float16*)(wbase + 1632);
    const float*    b1v = wbase + 5728;
    const float*    W2v = wbase + 5856;
    const float*    b2v = wbase + 5984;

    int p = blockIdx.x * 256 + threadIdx.x;
    p = min(p, M - 1);

    float x = gld(dt, coords, p * 3 + 0);
    float y = gld(dt, coords, p * 3 + 1);
    float z = gld(dt, coords, p * 3 + 2);

    Samp sx = make_samp(x, 128), sy = make_samp(y, 128), sz = make_samp(z, 128);

    float feat[40];
#pragma unroll
    for (int o = 0; o < 40; ++o) feat[o] = 0.0f;

    const void* Ls[3] = {lx, ly, lz};
    const void* Psv[3] = {pyz, pxz, pxy};
    Samp sl3[3] = {sx, sy, sz};
    Samp sa3[3] = {sy, sx, sx};
    Samp sb3[3] = {sz, sz, sy};
#pragma unroll 1
    for (int m = 0; m < 3; ++m) {
        float ta[32], tb[32];
        const float* bvt = bv + m * 32;
        const _Float16* Wt = WtH + m * 1024;
#pragma unroll
        for (int o = 0; o < 32; ++o) { ta[o] = bvt[o]; tb[o] = bvt[o]; }
        Samp sl = sl3[m], sa = sa3[m], sb = sb3[m];
        float w00 = sb.w0 * sa.w0, w01 = sb.w0 * sa.w1;
        float w10 = sb.w1 * sa.w0, w11 = sb.w1 * sa.w1;
        int i00 = sb.i0 * 128 + sa.i0, i01 = sb.i0 * 128 + sa.i1;
        int i10 = sb.i1 * 128 + sa.i0, i11 = sb.i1 * 128 + sa.i1;
#pragma unroll 1
        for (int c = 0; c < 32; ++c) {
            float el = sl.w0 * gld(dt, Ls[m], c * 128 + sl.i0)
                     + sl.w1 * gld(dt, Ls[m], c * 128 + sl.i1);
            float ep = w00 * gld(dt, Psv[m], c * 16384 + i00)
                     + w01 * gld(dt, Psv[m], c * 16384 + i01)
                     + w10 * gld(dt, Psv[m], c * 16384 + i10)
                     + w11 * gld(dt, Psv[m], c * 16384 + i11);
            float r1 = fmaxf(el, 0.0f), r2 = fmaxf(ep, 0.0f);
#pragma unroll
            for (int o = 0; o < 32; ++o) {
                float w = (float)Wt[o * 32 + c];
                ta[o] = fmaf(r1, w, ta[o]);
                tb[o] = fmaf(r2, w, tb[o]);
            }
        }
#pragma unroll
        for (int o = 0; o < 32; ++o) feat[o] = fmaf(ta[o], tb[o], feat[o]);
    }

    Samp vx = make_samp(x, 64), vy = make_samp(y, 64), vz = make_samp(z, 64);
#pragma unroll 1
    for (int corner = 0; corner < 8; ++corner) {
        int dx = corner & 1, dy = (corner >> 1) & 1, dz = corner >> 2;
        int xi = dx ? vx.i1 : vx.i0;
        int yi = dy ? vy.i1 : vy.i0;
        int zi = dz ? vz.i1 : vz.i0;
        float w = (dx ? vx.w1 : vx.w0) * (dy ? vy.w1 : vy.w0) * (dz ? vz.w1 : vz.w0);
        int pos = ((zi * 64) + yi) * 64 + xi;
#pragma unroll
        for (int c = 0; c < 8; ++c)
            feat[32 + c] = fmaf(w, gld(dt, vol, c * 262144 + pos), feat[32 + c]);
    }

    float acc_out = b2v[0];
#pragma unroll 2
    for (int j = 0; j < 128; ++j) {
        float acc = b1v[j];
        const _Float16* wr = W1H + j * 64;
#pragma unroll
        for (int i = 0; i < 40; ++i)
            acc = fmaf(feat[i], (float)wr[i], acc);
        acc_out = fmaf(fmaxf(acc, 0.0f), W2v[j], acc_out);
    }
    if (dt) ((float*)out)[p] = acc_out;
    else    ((u16*)out)[p] = f2bf(acc_out);
}

// =====================================================================
extern "C" void kernel_launch(void* const* d_in, const int* in_sizes, int n_in,
                              void* d_out, int out_size, void* d_ws, size_t ws_size,
                              hipStream_t stream) {
    const void* coords = d_in[0];
    const void* lx  = d_in[1];
    const void* ly  = d_in[2];
    const void* lz  = d_in[3];
    const void* pxy = d_in[4];
    const void* pyz = d_in[5];
    const void* pxz = d_in[6];
    const void* vol = d_in[7];
    const void* Wx  = d_in[8];
    const void* bx  = d_in[9];
    const void* Wy  = d_in[10];
    const void* by  = d_in[11];
    const void* Wz  = d_in[12];
    const void* bz  = d_in[13];
    const void* W1  = d_in[14];
    const void* b1  = d_in[15];
    const void* W2  = d_in[16];
    const void* b2  = d_in[17];

    int M = in_sizes[0] / 3;

    char* ws = (char*)d_ws;
    float*        wbase    = (float*)(ws + WF_OFF);
    u16*          planes_s = (u16*)(ws + PLANES_S_OFF);
    u16*          vol_s    = (u16*)(ws + VOL_S_OFF);
    u16*          lines_s  = (u16*)(ws + LINES_S_OFF);
    u16*          part     = (u16*)(ws + PART_OFF);
    unsigned int* tot      = (unsigned int*)(ws + TOT_OFF);
    int*          order    = (int*)(ws + ORDER_OFF);
    u16*          scoords  = (u16*)(ws + ORDER_OFF + (size_t)M * 4u);

    size_t need_sorted = (size_t)ORDER_OFF + (size_t)M * 4u + (size_t)M * 6u;

    if (ws_size >= need_sorted) {
        kp_prep_all<<<2100, 256, 0, stream>>>(coords, lx, ly, lz, pxy, pyz, pxz, vol,
                                              Wx, bx, Wy, by, Wz, bz, W1, b1, W2, b2,
                                              wbase, planes_s, vol_s, lines_s, part, M);
        kp_colscan<<<64, 64, 0, stream>>>(part, tot);
        kp_scatter_det<<<HBLOCKS, 256, 0, stream>>>(coords, part, tot, order,
                                                    scoords, M);
        int blocks64 = (M + 63) / 64;
        kp_main_mfma<<<blocks64, 64, 0, stream>>>(coords, order, scoords,
                                                  planes_s, vol_s,
                                                  lines_s, wbase, d_out, M);
    } else {
        int blocks = (M + 255) / 256;
        kp_prep_weights_fb<<<46, 256, 0, stream>>>(coords, Wx, bx, Wy, by, Wz, bz,
                                                   W1, b1, W2, b2, wbase);
        kp_main_direct<<<blocks, 256, 0, stream>>>(coords, lx, ly, lz, pxy, pyz, pxz,
                                                   vol, wbase, d_out, M);
    }
}